// Round 10
// baseline (161.974 us; speedup 1.0000x reference)
//
#include <hip/hip_runtime.h>
#include <hip/hip_bf16.h>

#define N_SAMPLES 262144
#define NUM_FLOWS 8
#define BLOCK 256
#define WAVES 4
#define MT 2                                    // 16-sample col-tiles per wave
#define SAMPLES_PER_BLOCK (WAVES * MT * 16)     // 128
#define NBLOCKS (N_SAMPLES / SAMPLES_PER_BLOCK) // 2048

// d_ws layout: [0 .. 3839] fp32 param block, then W2 bf16 frag block (64 KB)
#define WS_PARAMS 3840
#define OFF_W1   0
#define OFF_B1   512
#define OFF_B2   1024
#define OFF_W3   1536      // 8 flows x 256, [f][j][o]
#define OFF_B3   3584      // 32
#define OFF_CONST 3616     // 8 flows x 16: wm[9], els[3], sh[3], pad
#define OFF_LC   3744      // 12
#define OFF_MEAN 3756      // 3
#define OFF_LDB  3759      // 1
#define WS_W2_BYTE_OFF (WS_PARAMS * 4)  // 15360

typedef __attribute__((ext_vector_type(8))) short bf16x8;
typedef __attribute__((ext_vector_type(4))) short shortx4;
typedef __attribute__((ext_vector_type(4))) float floatx4;

union FragU { bf16x8 v; __hip_bfloat162 p[4]; };
union S4U   { shortx4 v; __hip_bfloat16 e[4]; };

__device__ __forceinline__ float b2f(__hip_bfloat16 x) { return __bfloat162float(x); }

// dtype-flexible load/store; f32 flag is grid-uniform (sniffed from L_tril[0][1]==0).
__device__ __forceinline__ float ldv(const void* p, int i, bool f32) {
    return f32 ? ((const float*)p)[i] : b2f(((const __hip_bfloat16*)p)[i]);
}
__device__ __forceinline__ void stv(void* p, int i, float v, bool f32) {
    if (f32) ((float*)p)[i] = v;
    else ((__hip_bfloat16*)p)[i] = __float2bfloat16(v);
}

// ---------------- prep kernel: runs once per launch, 9 blocks ----------------
__global__ void prep_kernel(
    const void* __restrict__ g_L_tril,
    const void* __restrict__ g_base_mean,
    const void* __restrict__ g_an_log_scale,
    const void* __restrict__ g_an_shift,
    const void* __restrict__ g_perm_p,
    const void* __restrict__ g_sign_s,
    const void* __restrict__ g_lu_l,
    const void* __restrict__ g_lu_u,
    const void* __restrict__ g_lu_log_s,
    const void* __restrict__ g_W1,
    const void* __restrict__ g_b1,
    const void* __restrict__ g_W2,
    const void* __restrict__ g_b2,
    const void* __restrict__ g_W3,
    const void* __restrict__ g_b3,
    float* __restrict__ ws)
{
    const bool f32 = (((const float*)g_L_tril)[1] == 0.0f);
    const int f = blockIdx.x;
    const int tid = threadIdx.x;
    __hip_bfloat16* wsW2 = (__hip_bfloat16*)((char*)ws + WS_W2_BYTE_OFF);

    if (f < NUM_FLOWS) {
        // W2 -> bf16 MFMA-A-frag order. flow-local elem (n,k) ->
        // frag (kc=k>>5, jt=n>>4), lane ((k>>3)&3)*16 + (n&15), slot k&7
        for (int i4 = tid; i4 < 1024; i4 += BLOCK) {
            int e = i4 << 2;
            int n = e >> 6, k = e & 63;
            int dst = ((k >> 5) * 4 + (n >> 4)) * 512 + (((k >> 3) & 3) * 16 + (n & 15)) * 8 + (k & 7);
            S4U u;
            if (f32) {
                float4 v = ((const float4*)g_W2)[f * 1024 + i4];
                u.e[0] = __float2bfloat16(v.x);
                u.e[1] = __float2bfloat16(v.y);
                u.e[2] = __float2bfloat16(v.z);
                u.e[3] = __float2bfloat16(v.w);
            } else {
                u.v = ((const shortx4*)g_W2)[f * 1024 + i4];
            }
            *(shortx4*)&wsW2[f * 4096 + dst] = u.v;
        }
        if (tid < 64) {
            ws[OFF_W1 + f * 64 + tid] = ldv(g_W1, f * 64 + tid, f32);
            ws[OFF_B1 + f * 64 + tid] = ldv(g_b1, f * 64 + tid, f32);
            ws[OFF_B2 + f * 64 + tid] = ldv(g_b2, f * 64 + tid, f32);
        }
        {   // W3 transposed [j][o]
            int o = tid >> 6, n = tid & 63;
            ws[OFF_W3 + f * 256 + n * 4 + o] = ldv(g_W3, f * 256 + o * 64 + n, f32);
        }
        if (tid < 4) ws[OFF_B3 + f * 4 + tid] = ldv(g_b3, f * 4 + tid, f32);
        if (tid == 0) {
            for (int d = 0; d < 3; ++d) {
                float ls = ldv(g_an_log_scale, f * 3 + d, f32);
                ws[OFF_CONST + f * 16 + 9 + d]  = __expf(ls);
                ws[OFF_CONST + f * 16 + 12 + d] = ldv(g_an_shift, f * 3 + d, f32);
            }
            float U[3][3], Lm[3][3], M[3][3], P[3][3];
            for (int i = 0; i < 3; ++i)
                for (int j = 0; j < 3; ++j) {
                    U[i][j]  = (j > i) ? ldv(g_lu_u, f * 9 + i * 3 + j, f32) : 0.f;
                    Lm[i][j] = (j < i) ? ldv(g_lu_l, f * 9 + i * 3 + j, f32) : (i == j ? 1.f : 0.f);
                    P[i][j]  = ldv(g_perm_p, f * 9 + i * 3 + j, f32);
                }
            for (int i = 0; i < 3; ++i)
                U[i][i] = ldv(g_sign_s, f * 3 + i, f32) * __expf(ldv(g_lu_log_s, f * 3 + i, f32));
            for (int i = 0; i < 3; ++i)
                for (int j = 0; j < 3; ++j) {
                    float s = 0.f;
                    for (int k = 0; k < 3; ++k) s += Lm[i][k] * U[k][j];
                    M[i][j] = s;
                }
            for (int i = 0; i < 3; ++i)
                for (int j = 0; j < 3; ++j) {
                    float s = 0.f;
                    for (int k = 0; k < 3; ++k) s += P[i][k] * M[k][j];
                    ws[OFF_CONST + f * 16 + i * 3 + j] = s;
                }
            ws[OFF_CONST + f * 16 + 15] = 0.f;
        }
    } else if (tid == 0) {
        // cholesky of cov = Lt Lt^T, mean, ldBase
        float Lt[3][3];
        for (int i = 0; i < 3; ++i)
            for (int j = 0; j < 3; ++j)
                Lt[i][j] = (j <= i) ? ldv(g_L_tril, i * 3 + j, f32) : 0.f;
        for (int i = 0; i < 3; ++i) Lt[i][i] += 1e-6f;
        float cov[3][3];
        for (int i = 0; i < 3; ++i)
            for (int j = 0; j < 3; ++j) {
                float s = 0.f;
                for (int k = 0; k < 3; ++k) s += Lt[i][k] * Lt[j][k];
                cov[i][j] = s;
            }
        float c00 = sqrtf(cov[0][0]);
        float c10 = cov[1][0] / c00, c20 = cov[2][0] / c00;
        float c11 = sqrtf(cov[1][1] - c10 * c10);
        float c21 = (cov[2][1] - c20 * c10) / c11;
        float c22 = sqrtf(cov[2][2] - c20 * c20 - c21 * c21);
        ws[OFF_LC + 0] = c00; ws[OFF_LC + 3] = c10; ws[OFF_LC + 4] = c11;
        ws[OFF_LC + 6] = c20; ws[OFF_LC + 7] = c21; ws[OFF_LC + 8] = c22;
        ws[OFF_LC + 1] = 0.f; ws[OFF_LC + 2] = 0.f; ws[OFF_LC + 5] = 0.f;
        ws[OFF_LC + 9] = 0.f; ws[OFF_LC + 10] = 0.f; ws[OFF_LC + 11] = 0.f;
        for (int d = 0; d < 3; ++d) ws[OFF_MEAN + d] = ldv(g_base_mean, d, f32);
        float ldb = 0.f;
        for (int i = 0; i < NUM_FLOWS * 3; ++i)
            ldb += ldv(g_an_log_scale, i, f32) + ldv(g_lu_log_s, i, f32);
        ws[OFF_LDB] = ldb;
    }
}

// ---------------- main kernel: zero LDS, zero barriers ----------------
// All weights stream from the prep-formatted ws (L1/L2-hot, ~84 KB working
// set). launch_bounds (256,2): the only empirically spill-free setting
// (r4/r7/r9); (256,3)/(256,4) triggered 86-144 MB scratch (r5/r6).
__global__ __launch_bounds__(BLOCK, 2) void glow_kernel(
    const void* __restrict__ g_eps,
    const void* __restrict__ g_L_tril,
    const float* __restrict__ ws,
    void* __restrict__ g_out)
{
    const bool f32 = (((const float*)g_L_tril)[1] == 0.0f);
    const __hip_bfloat16* wsW2 = (const __hip_bfloat16*)((const char*)ws + WS_W2_BYTE_OFF);

    const int tid  = threadIdx.x;
    const int lane = tid & 63;
    const int wave = tid >> 6;
    const int quad = lane >> 4;
    const int col  = lane & 15;
    const int base = blockIdx.x * SAMPLES_PER_BLOCK + wave * (MT * 16);

    // z init (col layout: sample = base + mt*16 + col, replicated over quads)
    float zc0[MT], zc1[MT], zc2[MT], lda[MT];
    {
        const float l00 = ws[OFF_LC + 0], l10 = ws[OFF_LC + 3], l11 = ws[OFF_LC + 4];
        const float l20 = ws[OFF_LC + 6], l21 = ws[OFF_LC + 7], l22 = ws[OFF_LC + 8];
        const float m0 = ws[OFF_MEAN], m1 = ws[OFF_MEAN + 1], m2 = ws[OFF_MEAN + 2];
#pragma unroll
        for (int mt = 0; mt < MT; ++mt) {
            int g = base + mt * 16 + col;
            float e0 = ldv(g_eps, g * 3 + 0, f32);
            float e1 = ldv(g_eps, g * 3 + 1, f32);
            float e2 = ldv(g_eps, g * 3 + 2, f32);
            zc0[mt] = m0 + l00 * e0;
            zc1[mt] = m1 + l10 * e0 + l11 * e1;
            zc2[mt] = m2 + l20 * e0 + l21 * e1 + l22 * e2;
            lda[mt] = 0.f;
        }
    }

#pragma unroll 1
    for (int f = 0; f < NUM_FLOWS; ++f) {
        // ---- issue A-frag + const loads FIRST (global, L1/L2-hot);
        // the independent affine + layer-1 VALU below hides their latency ----
        bf16x8 Af[2][4];
#pragma unroll
        for (int kc = 0; kc < 2; ++kc)
#pragma unroll
            for (int jt = 0; jt < 4; ++jt)
                Af[kc][jt] = *(const bf16x8*)&wsW2[f * 4096 + ((kc * 4 + jt) * 64 + lane) * 8];

        const floatx4* cp = (const floatx4*)&ws[OFF_CONST + f * 16];
        floatx4 c0 = cp[0], c1 = cp[1], c2 = cp[2], c3 = cp[3];

        // actnorm + 1x1 affine (fp32)
#pragma unroll
        for (int mt = 0; mt < MT; ++mt) {
            float t0 = c2[1] * (zc0[mt] + c3[0]);
            float t1 = c2[2] * (zc1[mt] + c3[1]);
            float t2 = c2[3] * (zc2[mt] + c3[2]);
            zc0[mt] = c0[0] * t0 + c0[1] * t1 + c0[2] * t2;
            zc1[mt] = c0[3] * t0 + c1[0] * t1 + c1[1] * t2;
            zc2[mt] = c1[2] * t0 + c1[3] * t1 + c2[0] * t2;
        }

        // layer 1 -> bf16 B fragments: h[k = kc*32+quad*8+i][m = col]
        FragU hB[MT][2];
#pragma unroll
        for (int kc = 0; kc < 2; ++kc) {
            const floatx4* w1p = (const floatx4*)&ws[OFF_W1 + f * 64 + kc * 32 + quad * 8];
            const floatx4* b1p = (const floatx4*)&ws[OFF_B1 + f * 64 + kc * 32 + quad * 8];
            floatx4 w1a = w1p[0], w1b = w1p[1];
            floatx4 b1a = b1p[0], b1b = b1p[1];
#pragma unroll
            for (int mt = 0; mt < MT; ++mt) {
                float z0 = zc0[mt];
#pragma unroll
                for (int w = 0; w < 2; ++w) {
                    float a0 = fmaxf(fmaf(z0, w1a[2 * w],     b1a[2 * w]),     0.f);
                    float a1 = fmaxf(fmaf(z0, w1a[2 * w + 1], b1a[2 * w + 1]), 0.f);
                    float b0 = fmaxf(fmaf(z0, w1b[2 * w],     b1b[2 * w]),     0.f);
                    float b1 = fmaxf(fmaf(z0, w1b[2 * w + 1], b1b[2 * w + 1]), 0.f);
                    hB[mt][kc].p[w]     = __float22bfloat162_rn(make_float2(a0, a1));
                    hB[mt][kc].p[2 + w] = __float22bfloat162_rn(make_float2(b0, b1));
                }
            }
        }

        // layer 2: h2^T = W2 @ h^T (A = W2 frags, B = h frags), b2 in acc-init
        // layer-3 partials over this lane's 16 neurons
        float po[MT][4];
#pragma unroll
        for (int mt = 0; mt < MT; ++mt)
#pragma unroll
            for (int o = 0; o < 4; ++o) po[mt][o] = 0.f;

#pragma unroll
        for (int jt = 0; jt < 4; ++jt) {
            floatx4 b2q = *(const floatx4*)&ws[OFF_B2 + f * 64 + jt * 16 + quad * 4];
            floatx4 w3q[4];
#pragma unroll
            for (int r = 0; r < 4; ++r)
                w3q[r] = *(const floatx4*)&ws[OFF_W3 + f * 256 + (jt * 16 + quad * 4 + r) * 4];
#pragma unroll
            for (int mt = 0; mt < MT; ++mt) {
                floatx4 acc = b2q;
                acc = __builtin_amdgcn_mfma_f32_16x16x32_bf16(Af[0][jt], hB[mt][0].v, acc, 0, 0, 0);
                acc = __builtin_amdgcn_mfma_f32_16x16x32_bf16(Af[1][jt], hB[mt][1].v, acc, 0, 0, 0);
#pragma unroll
                for (int r = 0; r < 4; ++r) {
                    float h2 = fmaxf(acc[r], 0.f);
                    po[mt][0] = fmaf(w3q[r][0], h2, po[mt][0]);
                    po[mt][1] = fmaf(w3q[r][1], h2, po[mt][1]);
                    po[mt][2] = fmaf(w3q[r][2], h2, po[mt][2]);
                    po[mt][3] = fmaf(w3q[r][3], h2, po[mt][3]);
                }
            }
        }

        // reduce over the 4 quads (each quad holds 16 of the 64 neurons)
#pragma unroll
        for (int mt = 0; mt < MT; ++mt)
#pragma unroll
            for (int o = 0; o < 4; ++o) {
                float v = po[mt][o];
                v += __shfl_xor(v, 16);
                v += __shfl_xor(v, 32);
                po[mt][o] = v;
            }

        floatx4 b3v = *(const floatx4*)&ws[OFF_B3 + f * 4];
#pragma unroll
        for (int mt = 0; mt < MT; ++mt) {
            float sh0 = po[mt][0] + b3v[0];
            float sh1 = po[mt][1] + b3v[1];
            float ls0 = po[mt][2] + b3v[2];
            float ls1 = po[mt][3] + b3v[3];
            zc1[mt] = fmaf(zc1[mt], __expf(ls0), sh0);
            zc2[mt] = fmaf(zc2[mt], __expf(ls1), sh1);
            lda[mt] += ls0 + ls1;
        }
    }

    if (quad == 0) {
        const float ldBase = ws[OFF_LDB];
#pragma unroll
        for (int mt = 0; mt < MT; ++mt) {
            int g = base + mt * 16 + col;
            float z1 = zc1[mt], z2 = zc2[mt];
            stv(g_out, g * 3 + 0, zc0[mt], f32);
            stv(g_out, g * 3 + 1, __expf(z1), f32);
            stv(g_out, g * 3 + 2, __expf(z2), f32);
            stv(g_out, 3 * N_SAMPLES + g, lda[mt] + ldBase + z1 + z2, f32);
        }
    }
}

extern "C" void kernel_launch(void* const* d_in, const int* in_sizes, int n_in,
                              void* d_out, int out_size, void* d_ws, size_t ws_size,
                              hipStream_t stream) {
    prep_kernel<<<dim3(NUM_FLOWS + 1), dim3(BLOCK), 0, stream>>>(
        d_in[1], d_in[2], d_in[3], d_in[4], d_in[5], d_in[6], d_in[7],
        d_in[8], d_in[9], d_in[10], d_in[11], d_in[12], d_in[13], d_in[14], d_in[15],
        (float*)d_ws);
    glow_kernel<<<dim3(NBLOCKS), dim3(BLOCK), 0, stream>>>(
        d_in[0], d_in[1], (const float*)d_ws, d_out);
}

// Round 11
// 143.073 us; speedup vs baseline: 1.1321x; 1.1321x over previous
//
#include <hip/hip_runtime.h>
#include <hip/hip_bf16.h>

#define N_SAMPLES 262144
#define NUM_FLOWS 8
#define BLOCK 256
#define WAVES 4
#define MT 4                                    // 16-sample col-tiles per wave
#define SAMPLES_PER_BLOCK (WAVES * MT * 16)     // 256
#define NBLOCKS (N_SAMPLES / SAMPLES_PER_BLOCK) // 1024

// d_ws layout: [0 .. 3839] fp32 param block, then W2 bf16 frag block (64 KB)
#define WS_PARAMS 3840
#define OFF_W1   0
#define OFF_B1   512
#define OFF_B2   1024
#define OFF_W3   1536      // 8 flows x 256, [f][j][o]
#define OFF_B3   3584      // 32
#define OFF_CONST 3616     // 8 flows x 16: wm[9], els[3], sh[3], pad
#define OFF_LC   3744      // 12
#define OFF_MEAN 3756      // 3
#define OFF_LDB  3759      // 1
#define WS_W2_BYTE_OFF (WS_PARAMS * 4)  // 15360

typedef __attribute__((ext_vector_type(8))) short bf16x8;
typedef __attribute__((ext_vector_type(4))) short shortx4;
typedef __attribute__((ext_vector_type(4))) float floatx4;

union FragU { bf16x8 v; __hip_bfloat162 p[4]; };
union S4U   { shortx4 v; __hip_bfloat16 e[4]; };

__device__ __forceinline__ float b2f(__hip_bfloat16 x) { return __bfloat162float(x); }

// dtype-flexible load/store; f32 flag is grid-uniform (sniffed from L_tril[0][1]==0).
__device__ __forceinline__ float ldv(const void* p, int i, bool f32) {
    return f32 ? ((const float*)p)[i] : b2f(((const __hip_bfloat16*)p)[i]);
}
__device__ __forceinline__ void stv(void* p, int i, float v, bool f32) {
    if (f32) ((float*)p)[i] = v;
    else ((__hip_bfloat16*)p)[i] = __float2bfloat16(v);
}

// ---------------- prep kernel: runs once per launch, 9 blocks ----------------
__global__ void prep_kernel(
    const void* __restrict__ g_L_tril,
    const void* __restrict__ g_base_mean,
    const void* __restrict__ g_an_log_scale,
    const void* __restrict__ g_an_shift,
    const void* __restrict__ g_perm_p,
    const void* __restrict__ g_sign_s,
    const void* __restrict__ g_lu_l,
    const void* __restrict__ g_lu_u,
    const void* __restrict__ g_lu_log_s,
    const void* __restrict__ g_W1,
    const void* __restrict__ g_b1,
    const void* __restrict__ g_W2,
    const void* __restrict__ g_b2,
    const void* __restrict__ g_W3,
    const void* __restrict__ g_b3,
    float* __restrict__ ws)
{
    const bool f32 = (((const float*)g_L_tril)[1] == 0.0f);
    const int f = blockIdx.x;
    const int tid = threadIdx.x;
    __hip_bfloat16* wsW2 = (__hip_bfloat16*)((char*)ws + WS_W2_BYTE_OFF);

    if (f < NUM_FLOWS) {
        // W2 -> bf16 MFMA-A-frag order. flow-local elem (n,k) ->
        // frag (kc=k>>5, jt=n>>4), lane ((k>>3)&3)*16 + (n&15), slot k&7
        for (int i4 = tid; i4 < 1024; i4 += BLOCK) {
            int e = i4 << 2;
            int n = e >> 6, k = e & 63;
            int dst = ((k >> 5) * 4 + (n >> 4)) * 512 + (((k >> 3) & 3) * 16 + (n & 15)) * 8 + (k & 7);
            S4U u;
            if (f32) {
                float4 v = ((const float4*)g_W2)[f * 1024 + i4];
                u.e[0] = __float2bfloat16(v.x);
                u.e[1] = __float2bfloat16(v.y);
                u.e[2] = __float2bfloat16(v.z);
                u.e[3] = __float2bfloat16(v.w);
            } else {
                u.v = ((const shortx4*)g_W2)[f * 1024 + i4];
            }
            *(shortx4*)&wsW2[f * 4096 + dst] = u.v;
        }
        if (tid < 64) {
            ws[OFF_W1 + f * 64 + tid] = ldv(g_W1, f * 64 + tid, f32);
            ws[OFF_B1 + f * 64 + tid] = ldv(g_b1, f * 64 + tid, f32);
            ws[OFF_B2 + f * 64 + tid] = ldv(g_b2, f * 64 + tid, f32);
        }
        {   // W3 transposed [j][o]
            int o = tid >> 6, n = tid & 63;
            ws[OFF_W3 + f * 256 + n * 4 + o] = ldv(g_W3, f * 256 + o * 64 + n, f32);
        }
        if (tid < 4) ws[OFF_B3 + f * 4 + tid] = ldv(g_b3, f * 4 + tid, f32);
        if (tid == 0) {
            for (int d = 0; d < 3; ++d) {
                float ls = ldv(g_an_log_scale, f * 3 + d, f32);
                ws[OFF_CONST + f * 16 + 9 + d]  = __expf(ls);
                ws[OFF_CONST + f * 16 + 12 + d] = ldv(g_an_shift, f * 3 + d, f32);
            }
            float U[3][3], Lm[3][3], M[3][3], P[3][3];
            for (int i = 0; i < 3; ++i)
                for (int j = 0; j < 3; ++j) {
                    U[i][j]  = (j > i) ? ldv(g_lu_u, f * 9 + i * 3 + j, f32) : 0.f;
                    Lm[i][j] = (j < i) ? ldv(g_lu_l, f * 9 + i * 3 + j, f32) : (i == j ? 1.f : 0.f);
                    P[i][j]  = ldv(g_perm_p, f * 9 + i * 3 + j, f32);
                }
            for (int i = 0; i < 3; ++i)
                U[i][i] = ldv(g_sign_s, f * 3 + i, f32) * __expf(ldv(g_lu_log_s, f * 3 + i, f32));
            for (int i = 0; i < 3; ++i)
                for (int j = 0; j < 3; ++j) {
                    float s = 0.f;
                    for (int k = 0; k < 3; ++k) s += Lm[i][k] * U[k][j];
                    M[i][j] = s;
                }
            for (int i = 0; i < 3; ++i)
                for (int j = 0; j < 3; ++j) {
                    float s = 0.f;
                    for (int k = 0; k < 3; ++k) s += P[i][k] * M[k][j];
                    ws[OFF_CONST + f * 16 + i * 3 + j] = s;
                }
            ws[OFF_CONST + f * 16 + 15] = 0.f;
        }
    } else if (tid == 0) {
        // cholesky of cov = Lt Lt^T, mean, ldBase
        float Lt[3][3];
        for (int i = 0; i < 3; ++i)
            for (int j = 0; j < 3; ++j)
                Lt[i][j] = (j <= i) ? ldv(g_L_tril, i * 3 + j, f32) : 0.f;
        for (int i = 0; i < 3; ++i) Lt[i][i] += 1e-6f;
        float cov[3][3];
        for (int i = 0; i < 3; ++i)
            for (int j = 0; j < 3; ++j) {
                float s = 0.f;
                for (int k = 0; k < 3; ++k) s += Lt[i][k] * Lt[j][k];
                cov[i][j] = s;
            }
        float c00 = sqrtf(cov[0][0]);
        float c10 = cov[1][0] / c00, c20 = cov[2][0] / c00;
        float c11 = sqrtf(cov[1][1] - c10 * c10);
        float c21 = (cov[2][1] - c20 * c10) / c11;
        float c22 = sqrtf(cov[2][2] - c20 * c20 - c21 * c21);
        ws[OFF_LC + 0] = c00; ws[OFF_LC + 3] = c10; ws[OFF_LC + 4] = c11;
        ws[OFF_LC + 6] = c20; ws[OFF_LC + 7] = c21; ws[OFF_LC + 8] = c22;
        ws[OFF_LC + 1] = 0.f; ws[OFF_LC + 2] = 0.f; ws[OFF_LC + 5] = 0.f;
        ws[OFF_LC + 9] = 0.f; ws[OFF_LC + 10] = 0.f; ws[OFF_LC + 11] = 0.f;
        for (int d = 0; d < 3; ++d) ws[OFF_MEAN + d] = ldv(g_base_mean, d, f32);
        float ldb = 0.f;
        for (int i = 0; i < NUM_FLOWS * 3; ++i)
            ldb += ldv(g_an_log_scale, i, f32) + ldv(g_lu_log_s, i, f32);
        ws[OFF_LDB] = ldb;
    }
}

// ---------------- main kernel ----------------
// r9 structure (params in LDS — r10 zero-LDS variant regressed: 47 KB working
// set overflows 32 KB L1, global table reads became ~200cyc L2 hits).
// launch_bounds (256,2): the only empirically spill-free setting (r4/r7/r9);
// (256,3)/(256,4) triggered 86-144 MB scratch (r5/r6).
__global__ __launch_bounds__(BLOCK, 2) void glow_kernel(
    const void* __restrict__ g_eps,
    const void* __restrict__ g_L_tril,
    const float* __restrict__ ws,
    void* __restrict__ g_out)
{
    const bool f32 = (((const float*)g_L_tril)[1] == 0.0f);

    // one contiguous conflict-free copy of the 15 KB param block; ONE barrier.
    __shared__ __align__(16) float sP[WS_PARAMS];
    for (int i = threadIdx.x; i < WS_PARAMS / 4; i += BLOCK)
        ((float4*)sP)[i] = ((const float4*)ws)[i];
    __syncthreads();

    const __hip_bfloat16* wsW2 = (const __hip_bfloat16*)((const char*)ws + WS_W2_BYTE_OFF);

    const int tid  = threadIdx.x;
    const int lane = tid & 63;
    const int wave = tid >> 6;
    const int quad = lane >> 4;
    const int col  = lane & 15;
    const int base = blockIdx.x * SAMPLES_PER_BLOCK + wave * (MT * 16);

    // z init (col layout: sample = base + mt*16 + col, replicated over quads)
    float zc0[MT], zc1[MT], zc2[MT], lda[MT];
    {
        const float l00 = sP[OFF_LC + 0], l10 = sP[OFF_LC + 3], l11 = sP[OFF_LC + 4];
        const float l20 = sP[OFF_LC + 6], l21 = sP[OFF_LC + 7], l22 = sP[OFF_LC + 8];
        const float m0 = sP[OFF_MEAN], m1 = sP[OFF_MEAN + 1], m2 = sP[OFF_MEAN + 2];
#pragma unroll
        for (int mt = 0; mt < MT; ++mt) {
            int g = base + mt * 16 + col;
            float e0 = ldv(g_eps, g * 3 + 0, f32);
            float e1 = ldv(g_eps, g * 3 + 1, f32);
            float e2 = ldv(g_eps, g * 3 + 2, f32);
            zc0[mt] = m0 + l00 * e0;
            zc1[mt] = m1 + l10 * e0 + l11 * e1;
            zc2[mt] = m2 + l20 * e0 + l21 * e1 + l22 * e2;
            lda[mt] = 0.f;
        }
    }

#pragma unroll 1
    for (int f = 0; f < NUM_FLOWS; ++f) {
        // A-frag loads issued early (global, L2-hot, lane-contiguous)
        bf16x8 Af[2][4];
#pragma unroll
        for (int kc = 0; kc < 2; ++kc)
#pragma unroll
            for (int jt = 0; jt < 4; ++jt)
                Af[kc][jt] = *(const bf16x8*)&wsW2[f * 4096 + ((kc * 4 + jt) * 64 + lane) * 8];

        const floatx4* cp = (const floatx4*)&sP[OFF_CONST + f * 16];
        floatx4 c0 = cp[0], c1 = cp[1], c2 = cp[2], c3 = cp[3];

        // actnorm + 1x1 affine (fp32)
#pragma unroll
        for (int mt = 0; mt < MT; ++mt) {
            float t0 = c2[1] * (zc0[mt] + c3[0]);
            float t1 = c2[2] * (zc1[mt] + c3[1]);
            float t2 = c2[3] * (zc2[mt] + c3[2]);
            zc0[mt] = c0[0] * t0 + c0[1] * t1 + c0[2] * t2;
            zc1[mt] = c0[3] * t0 + c1[0] * t1 + c1[1] * t2;
            zc2[mt] = c1[2] * t0 + c1[3] * t1 + c2[0] * t2;
        }

        // layer 1 -> bf16 B fragments: h[k = kc*32+quad*8+i][m = col]
        FragU hB[MT][2];
#pragma unroll
        for (int kc = 0; kc < 2; ++kc) {
            const floatx4* w1p = (const floatx4*)&sP[OFF_W1 + f * 64 + kc * 32 + quad * 8];
            const floatx4* b1p = (const floatx4*)&sP[OFF_B1 + f * 64 + kc * 32 + quad * 8];
            floatx4 w1a = w1p[0], w1b = w1p[1];
            floatx4 b1a = b1p[0], b1b = b1p[1];
#pragma unroll
            for (int mt = 0; mt < MT; ++mt) {
                float z0 = zc0[mt];
#pragma unroll
                for (int w = 0; w < 2; ++w) {
                    float a0 = fmaxf(fmaf(z0, w1a[2 * w],     b1a[2 * w]),     0.f);
                    float a1 = fmaxf(fmaf(z0, w1a[2 * w + 1], b1a[2 * w + 1]), 0.f);
                    float b0 = fmaxf(fmaf(z0, w1b[2 * w],     b1b[2 * w]),     0.f);
                    float b1 = fmaxf(fmaf(z0, w1b[2 * w + 1], b1b[2 * w + 1]), 0.f);
                    hB[mt][kc].p[w]     = __float22bfloat162_rn(make_float2(a0, a1));
                    hB[mt][kc].p[2 + w] = __float22bfloat162_rn(make_float2(b0, b1));
                }
            }
        }

        // layer 2: h2^T = W2 @ h^T (A = W2 frags, B = h frags), b2 in acc-init
        // layer-3 partials over this lane's 16 neurons
        float po[MT][4];
#pragma unroll
        for (int mt = 0; mt < MT; ++mt)
#pragma unroll
            for (int o = 0; o < 4; ++o) po[mt][o] = 0.f;

#pragma unroll
        for (int jt = 0; jt < 4; ++jt) {
            floatx4 b2q = *(const floatx4*)&sP[OFF_B2 + f * 64 + jt * 16 + quad * 4];
#pragma unroll
            for (int mt = 0; mt < MT; ++mt) {
                floatx4 acc = b2q;
                acc = __builtin_amdgcn_mfma_f32_16x16x32_bf16(Af[0][jt], hB[mt][0].v, acc, 0, 0, 0);
                acc = __builtin_amdgcn_mfma_f32_16x16x32_bf16(Af[1][jt], hB[mt][1].v, acc, 0, 0, 0);
#pragma unroll
                for (int r = 0; r < 4; ++r) {
                    float h2 = fmaxf(acc[r], 0.f);
                    floatx4 w3 = *(const floatx4*)&sP[OFF_W3 + f * 256 + (jt * 16 + quad * 4 + r) * 4];
                    po[mt][0] = fmaf(w3[0], h2, po[mt][0]);
                    po[mt][1] = fmaf(w3[1], h2, po[mt][1]);
                    po[mt][2] = fmaf(w3[2], h2, po[mt][2]);
                    po[mt][3] = fmaf(w3[3], h2, po[mt][3]);
                }
            }
        }

        // reduce over the 4 quads (each quad holds 16 of the 64 neurons)
#pragma unroll
        for (int mt = 0; mt < MT; ++mt)
#pragma unroll
            for (int o = 0; o < 4; ++o) {
                float v = po[mt][o];
                v += __shfl_xor(v, 16);
                v += __shfl_xor(v, 32);
                po[mt][o] = v;
            }

        floatx4 b3v = *(const floatx4*)&sP[OFF_B3 + f * 4];
#pragma unroll
        for (int mt = 0; mt < MT; ++mt) {
            float sh0 = po[mt][0] + b3v[0];
            float sh1 = po[mt][1] + b3v[1];
            float ls0 = po[mt][2] + b3v[2];
            float ls1 = po[mt][3] + b3v[3];
            zc1[mt] = fmaf(zc1[mt], __expf(ls0), sh0);
            zc2[mt] = fmaf(zc2[mt], __expf(ls1), sh1);
            lda[mt] += ls0 + ls1;
        }
    }

    if (quad == 0) {
        const float ldBase = sP[OFF_LDB];
#pragma unroll
        for (int mt = 0; mt < MT; ++mt) {
            int g = base + mt * 16 + col;
            float z1 = zc1[mt], z2 = zc2[mt];
            stv(g_out, g * 3 + 0, zc0[mt], f32);
            stv(g_out, g * 3 + 1, __expf(z1), f32);
            stv(g_out, g * 3 + 2, __expf(z2), f32);
            stv(g_out, 3 * N_SAMPLES + g, lda[mt] + ldBase + z1 + z2, f32);
        }
    }
}

extern "C" void kernel_launch(void* const* d_in, const int* in_sizes, int n_in,
                              void* d_out, int out_size, void* d_ws, size_t ws_size,
                              hipStream_t stream) {
    prep_kernel<<<dim3(NUM_FLOWS + 1), dim3(BLOCK), 0, stream>>>(
        d_in[1], d_in[2], d_in[3], d_in[4], d_in[5], d_in[6], d_in[7],
        d_in[8], d_in[9], d_in[10], d_in[11], d_in[12], d_in[13], d_in[14], d_in[15],
        (float*)d_ws);
    glow_kernel<<<dim3(NBLOCKS), dim3(BLOCK), 0, stream>>>(
        d_in[0], d_in[1], (const float*)d_ws, d_out);
}

// Round 12
// 129.843 us; speedup vs baseline: 1.2475x; 1.1019x over previous
//
#include <hip/hip_runtime.h>
#include <hip/hip_bf16.h>

#define N_SAMPLES 262144
#define NUM_FLOWS 8
#define BLOCK 256
#define WAVES 4
#define MT 2                                    // 16-sample col-tiles per wave (r9 config; MT=4 regressed r11)
#define SAMPLES_PER_BLOCK (WAVES * MT * 16)     // 128
#define NBLOCKS (N_SAMPLES / SAMPLES_PER_BLOCK) // 2048

// d_ws float layout:
#define OFF_W1    0        // 512
#define OFF_B1    512      // 512
#define OFF_B2    1024     // 512
#define OFF_B3    1536     // 32
#define OFF_CONST 1568     // 8 x 16: wm[9], els[3], sh[3], pad
#define OFF_LC    1696     // 12
#define OFF_MEAN  1708     // 3
#define OFF_LDB   1711     // 1
#define OFF_A3    1728     // W3 A-frags, bf16: 8 flows x 2 frags x 64 lanes x 8 = 16 KB = 4096 floats
#define WS_PARAMS 5824     // floats (23296 B)
#define WS_W2_BYTE_OFF (WS_PARAMS * 4)  // 23296

typedef __attribute__((ext_vector_type(8))) short bf16x8;
typedef __attribute__((ext_vector_type(4))) short shortx4;
typedef __attribute__((ext_vector_type(4))) float floatx4;

union FragU { bf16x8 v; __hip_bfloat162 p[4]; __hip_bfloat16 e[8]; };
union S4U   { shortx4 v; __hip_bfloat16 e[4]; };

__device__ __forceinline__ float b2f(__hip_bfloat16 x) { return __bfloat162float(x); }

// dtype-flexible load/store; f32 flag is grid-uniform (sniffed from L_tril[0][1]==0).
__device__ __forceinline__ float ldv(const void* p, int i, bool f32) {
    return f32 ? ((const float*)p)[i] : b2f(((const __hip_bfloat16*)p)[i]);
}
__device__ __forceinline__ void stv(void* p, int i, float v, bool f32) {
    if (f32) ((float*)p)[i] = v;
    else ((__hip_bfloat16*)p)[i] = __float2bfloat16(v);
}

// ---------------- prep kernel: runs once per launch, 9 blocks ----------------
__global__ void prep_kernel(
    const void* __restrict__ g_L_tril,
    const void* __restrict__ g_base_mean,
    const void* __restrict__ g_an_log_scale,
    const void* __restrict__ g_an_shift,
    const void* __restrict__ g_perm_p,
    const void* __restrict__ g_sign_s,
    const void* __restrict__ g_lu_l,
    const void* __restrict__ g_lu_u,
    const void* __restrict__ g_lu_log_s,
    const void* __restrict__ g_W1,
    const void* __restrict__ g_b1,
    const void* __restrict__ g_W2,
    const void* __restrict__ g_b2,
    const void* __restrict__ g_W3,
    const void* __restrict__ g_b3,
    float* __restrict__ ws)
{
    const bool f32 = (((const float*)g_L_tril)[1] == 0.0f);
    const int f = blockIdx.x;
    const int tid = threadIdx.x;
    __hip_bfloat16* wsW2 = (__hip_bfloat16*)((char*)ws + WS_W2_BYTE_OFF);
    __hip_bfloat16* wsA3 = (__hip_bfloat16*)(ws + OFF_A3);

    if (f < NUM_FLOWS) {
        // W2 -> bf16 MFMA-A-frag order. flow-local elem (n,k) ->
        // frag (kc=k>>5, jt=n>>4), lane ((k>>3)&3)*16 + (n&15), slot k&7
        for (int i4 = tid; i4 < 1024; i4 += BLOCK) {
            int e = i4 << 2;
            int n = e >> 6, k = e & 63;
            int dst = ((k >> 5) * 4 + (n >> 4)) * 512 + (((k >> 3) & 3) * 16 + (n & 15)) * 8 + (k & 7);
            S4U u;
            if (f32) {
                float4 v = ((const float4*)g_W2)[f * 1024 + i4];
                u.e[0] = __float2bfloat16(v.x);
                u.e[1] = __float2bfloat16(v.y);
                u.e[2] = __float2bfloat16(v.z);
                u.e[3] = __float2bfloat16(v.w);
            } else {
                u.v = ((const shortx4*)g_W2)[f * 1024 + i4];
            }
            *(shortx4*)&wsW2[f * 4096 + dst] = u.v;
        }
        // W3 -> bf16 A-fragment with neuron relabeling:
        // layer-2 C position (jt,quad,r) [neuron n = jt*16+quad*4+r] packs into
        // layer-3 B position k3 = (jt&1)*32 + quad*8 + (jt>>1)*4 + r.
        // A3[m][k3] = W3[m][n(k3)] for m<4 else 0.
        if (tid < 128) {
            int kc2 = tid >> 6, L = tid & 63;
            int m = L & 15, qd = L >> 4;
            FragU fr;
#pragma unroll
            for (int j = 0; j < 8; ++j) {
                int jt = ((j >> 2) << 1) | kc2;
                int r  = j & 3;
                int n  = jt * 16 + qd * 4 + r;
                float v = (m < 4) ? ldv(g_W3, f * 256 + m * 64 + n, f32) : 0.f;
                fr.e[j] = __float2bfloat16(v);
            }
            *(bf16x8*)&wsA3[(f * 2 + kc2) * 512 + L * 8] = fr.v;
        }
        if (tid < 64) {
            ws[OFF_W1 + f * 64 + tid] = ldv(g_W1, f * 64 + tid, f32);
            ws[OFF_B1 + f * 64 + tid] = ldv(g_b1, f * 64 + tid, f32);
            ws[OFF_B2 + f * 64 + tid] = ldv(g_b2, f * 64 + tid, f32);
        }
        if (tid < 4) ws[OFF_B3 + f * 4 + tid] = ldv(g_b3, f * 4 + tid, f32);
        if (tid == 0) {
            for (int d = 0; d < 3; ++d) {
                float ls = ldv(g_an_log_scale, f * 3 + d, f32);
                ws[OFF_CONST + f * 16 + 9 + d]  = __expf(ls);
                ws[OFF_CONST + f * 16 + 12 + d] = ldv(g_an_shift, f * 3 + d, f32);
            }
            float U[3][3], Lm[3][3], M[3][3], P[3][3];
            for (int i = 0; i < 3; ++i)
                for (int j = 0; j < 3; ++j) {
                    U[i][j]  = (j > i) ? ldv(g_lu_u, f * 9 + i * 3 + j, f32) : 0.f;
                    Lm[i][j] = (j < i) ? ldv(g_lu_l, f * 9 + i * 3 + j, f32) : (i == j ? 1.f : 0.f);
                    P[i][j]  = ldv(g_perm_p, f * 9 + i * 3 + j, f32);
                }
            for (int i = 0; i < 3; ++i)
                U[i][i] = ldv(g_sign_s, f * 3 + i, f32) * __expf(ldv(g_lu_log_s, f * 3 + i, f32));
            for (int i = 0; i < 3; ++i)
                for (int j = 0; j < 3; ++j) {
                    float s = 0.f;
                    for (int k = 0; k < 3; ++k) s += Lm[i][k] * U[k][j];
                    M[i][j] = s;
                }
            for (int i = 0; i < 3; ++i)
                for (int j = 0; j < 3; ++j) {
                    float s = 0.f;
                    for (int k = 0; k < 3; ++k) s += P[i][k] * M[k][j];
                    ws[OFF_CONST + f * 16 + i * 3 + j] = s;
                }
            ws[OFF_CONST + f * 16 + 15] = 0.f;
        }
    } else if (tid == 0) {
        // cholesky of cov = Lt Lt^T, mean, ldBase
        float Lt[3][3];
        for (int i = 0; i < 3; ++i)
            for (int j = 0; j < 3; ++j)
                Lt[i][j] = (j <= i) ? ldv(g_L_tril, i * 3 + j, f32) : 0.f;
        for (int i = 0; i < 3; ++i) Lt[i][i] += 1e-6f;
        float cov[3][3];
        for (int i = 0; i < 3; ++i)
            for (int j = 0; j < 3; ++j) {
                float s = 0.f;
                for (int k = 0; k < 3; ++k) s += Lt[i][k] * Lt[j][k];
                cov[i][j] = s;
            }
        float c00 = sqrtf(cov[0][0]);
        float c10 = cov[1][0] / c00, c20 = cov[2][0] / c00;
        float c11 = sqrtf(cov[1][1] - c10 * c10);
        float c21 = (cov[2][1] - c20 * c10) / c11;
        float c22 = sqrtf(cov[2][2] - c20 * c20 - c21 * c21);
        ws[OFF_LC + 0] = c00; ws[OFF_LC + 3] = c10; ws[OFF_LC + 4] = c11;
        ws[OFF_LC + 6] = c20; ws[OFF_LC + 7] = c21; ws[OFF_LC + 8] = c22;
        ws[OFF_LC + 1] = 0.f; ws[OFF_LC + 2] = 0.f; ws[OFF_LC + 5] = 0.f;
        ws[OFF_LC + 9] = 0.f; ws[OFF_LC + 10] = 0.f; ws[OFF_LC + 11] = 0.f;
        for (int d = 0; d < 3; ++d) ws[OFF_MEAN + d] = ldv(g_base_mean, d, f32);
        float ldb = 0.f;
        for (int i = 0; i < NUM_FLOWS * 3; ++i)
            ldb += ldv(g_an_log_scale, i, f32) + ldv(g_lu_log_s, i, f32);
        ws[OFF_LDB] = ldb;
    }
}

// ---------------- main kernel ----------------
// r9 structure + layer-3 as MFMA (neuron-relabeled W3 A-frag) + uniform tables
// via scalar global reads. launch_bounds (256,2): the only spill-free setting
// (r4/r7/r9); (256,3)/(256,4) triggered 86-144 MB scratch (r5/r6).
__global__ __launch_bounds__(BLOCK, 2) void glow_kernel(
    const void* __restrict__ g_eps,
    const void* __restrict__ g_L_tril,
    const float* __restrict__ ws,
    void* __restrict__ g_out)
{
    const bool f32 = (((const float*)g_L_tril)[1] == 0.0f);

    // one contiguous conflict-free copy of the 23 KB param block; ONE barrier.
    __shared__ __align__(16) float sP[WS_PARAMS];
    for (int i = threadIdx.x; i < WS_PARAMS / 4; i += BLOCK)
        ((float4*)sP)[i] = ((const float4*)ws)[i];
    __syncthreads();

    const __hip_bfloat16* wsW2 = (const __hip_bfloat16*)((const char*)ws + WS_W2_BYTE_OFF);
    const char* sPb = (const char*)sP;

    const int tid  = threadIdx.x;
    const int lane = tid & 63;
    const int wave = tid >> 6;
    const int quad = lane >> 4;
    const int col  = lane & 15;
    const int base = blockIdx.x * SAMPLES_PER_BLOCK + wave * (MT * 16);

    // z init (col layout: sample = base + mt*16 + col, replicated over quads)
    float zc0[MT], zc1[MT], zc2[MT], lda[MT];
    {
        const float l00 = ws[OFF_LC + 0], l10 = ws[OFF_LC + 3], l11 = ws[OFF_LC + 4];
        const float l20 = ws[OFF_LC + 6], l21 = ws[OFF_LC + 7], l22 = ws[OFF_LC + 8];
        const float m0 = ws[OFF_MEAN], m1 = ws[OFF_MEAN + 1], m2 = ws[OFF_MEAN + 2];
#pragma unroll
        for (int mt = 0; mt < MT; ++mt) {
            int g = base + mt * 16 + col;
            float e0 = ldv(g_eps, g * 3 + 0, f32);
            float e1 = ldv(g_eps, g * 3 + 1, f32);
            float e2 = ldv(g_eps, g * 3 + 2, f32);
            zc0[mt] = m0 + l00 * e0;
            zc1[mt] = m1 + l10 * e0 + l11 * e1;
            zc2[mt] = m2 + l20 * e0 + l21 * e1 + l22 * e2;
            lda[mt] = 0.f;
        }
    }

#pragma unroll 1
    for (int f = 0; f < NUM_FLOWS; ++f) {
        // A-frag loads issued early (global, L2-hot, lane-contiguous)
        bf16x8 Af[2][4];
#pragma unroll
        for (int kc = 0; kc < 2; ++kc)
#pragma unroll
            for (int jt = 0; jt < 4; ++jt)
                Af[kc][jt] = *(const bf16x8*)&wsW2[f * 4096 + ((kc * 4 + jt) * 64 + lane) * 8];

        // W3 A3-frags from LDS (2 reads), b2 rows (4 reads)
        bf16x8 A3f[2];
#pragma unroll
        for (int kc2 = 0; kc2 < 2; ++kc2)
            A3f[kc2] = *(const bf16x8*)(sPb + OFF_A3 * 4 + ((f * 2 + kc2) * 64 + lane) * 16);
        floatx4 b2q[4];
#pragma unroll
        for (int jt = 0; jt < 4; ++jt)
            b2q[jt] = *(const floatx4*)&sP[OFF_B2 + f * 64 + jt * 16 + quad * 4];

        // wave-uniform tables straight from global (scalar loads, off LDS pipe)
        const floatx4* cp = (const floatx4*)&ws[OFF_CONST + f * 16];
        floatx4 c0 = cp[0], c1 = cp[1], c2 = cp[2], c3 = cp[3];
        floatx4 b3v = *(const floatx4*)&ws[OFF_B3 + f * 4];

        // actnorm + 1x1 affine (fp32)
#pragma unroll
        for (int mt = 0; mt < MT; ++mt) {
            float t0 = c2[1] * (zc0[mt] + c3[0]);
            float t1 = c2[2] * (zc1[mt] + c3[1]);
            float t2 = c2[3] * (zc2[mt] + c3[2]);
            zc0[mt] = c0[0] * t0 + c0[1] * t1 + c0[2] * t2;
            zc1[mt] = c0[3] * t0 + c1[0] * t1 + c1[1] * t2;
            zc2[mt] = c1[2] * t0 + c1[3] * t1 + c2[0] * t2;
        }

        // layer 1 -> bf16 B fragments: h[k = kc*32+quad*8+i][m = col]
        FragU hB[MT][2];
#pragma unroll
        for (int kc = 0; kc < 2; ++kc) {
            const floatx4* w1p = (const floatx4*)&sP[OFF_W1 + f * 64 + kc * 32 + quad * 8];
            const floatx4* b1p = (const floatx4*)&sP[OFF_B1 + f * 64 + kc * 32 + quad * 8];
            floatx4 w1a = w1p[0], w1b = w1p[1];
            floatx4 b1a = b1p[0], b1b = b1p[1];
#pragma unroll
            for (int mt = 0; mt < MT; ++mt) {
                float z0 = zc0[mt];
#pragma unroll
                for (int w = 0; w < 2; ++w) {
                    float a0 = fmaxf(fmaf(z0, w1a[2 * w],     b1a[2 * w]),     0.f);
                    float a1 = fmaxf(fmaf(z0, w1a[2 * w + 1], b1a[2 * w + 1]), 0.f);
                    float b0 = fmaxf(fmaf(z0, w1b[2 * w],     b1b[2 * w]),     0.f);
                    float b1 = fmaxf(fmaf(z0, w1b[2 * w + 1], b1b[2 * w + 1]), 0.f);
                    hB[mt][kc].p[w]     = __float22bfloat162_rn(make_float2(a0, a1));
                    hB[mt][kc].p[2 + w] = __float22bfloat162_rn(make_float2(b0, b1));
                }
            }
        }

        // layer 2 (MFMA, b2 as C-init) -> in-register repack -> layer 3 (MFMA)
#pragma unroll
        for (int mt = 0; mt < MT; ++mt) {
            floatx4 a2[4];
#pragma unroll
            for (int jt = 0; jt < 4; ++jt) {
                floatx4 acc = __builtin_amdgcn_mfma_f32_16x16x32_bf16(Af[0][jt], hB[mt][0].v, b2q[jt], 0, 0, 0);
                a2[jt] = __builtin_amdgcn_mfma_f32_16x16x32_bf16(Af[1][jt], hB[mt][1].v, acc, 0, 0, 0);
            }
            // relu + pack: C pos (jt,r) -> B3 frag kc2 = jt&1, elem (jt>>1)*4 + r
            FragU h3[2];
#pragma unroll
            for (int jt = 0; jt < 4; ++jt) {
                int kc2 = jt & 1, pb = (jt >> 1) * 2;
                h3[kc2].p[pb]     = __float22bfloat162_rn(make_float2(fmaxf(a2[jt][0], 0.f), fmaxf(a2[jt][1], 0.f)));
                h3[kc2].p[pb + 1] = __float22bfloat162_rn(make_float2(fmaxf(a2[jt][2], 0.f), fmaxf(a2[jt][3], 0.f)));
            }
            floatx4 acc3 = {0.f, 0.f, 0.f, 0.f};
            acc3 = __builtin_amdgcn_mfma_f32_16x16x32_bf16(A3f[0], h3[0].v, acc3, 0, 0, 0);
            acc3 = __builtin_amdgcn_mfma_f32_16x16x32_bf16(A3f[1], h3[1].v, acc3, 0, 0, 0);
            // results live in quad0 rows 0..3; broadcast to all quads
            float sh0 = __shfl(acc3[0], col) + b3v[0];
            float sh1 = __shfl(acc3[1], col) + b3v[1];
            float ls0 = __shfl(acc3[2], col) + b3v[2];
            float ls1 = __shfl(acc3[3], col) + b3v[3];
            zc1[mt] = fmaf(zc1[mt], __expf(ls0), sh0);
            zc2[mt] = fmaf(zc2[mt], __expf(ls1), sh1);
            lda[mt] += ls0 + ls1;
        }
    }

    if (quad == 0) {
        const float ldBase = ws[OFF_LDB];
#pragma unroll
        for (int mt = 0; mt < MT; ++mt) {
            int g = base + mt * 16 + col;
            float z1 = zc1[mt], z2 = zc2[mt];
            stv(g_out, g * 3 + 0, zc0[mt], f32);
            stv(g_out, g * 3 + 1, __expf(z1), f32);
            stv(g_out, g * 3 + 2, __expf(z2), f32);
            stv(g_out, 3 * N_SAMPLES + g, lda[mt] + ldBase + z1 + z2, f32);
        }
    }
}

extern "C" void kernel_launch(void* const* d_in, const int* in_sizes, int n_in,
                              void* d_out, int out_size, void* d_ws, size_t ws_size,
                              hipStream_t stream) {
    prep_kernel<<<dim3(NUM_FLOWS + 1), dim3(BLOCK), 0, stream>>>(
        d_in[1], d_in[2], d_in[3], d_in[4], d_in[5], d_in[6], d_in[7],
        d_in[8], d_in[9], d_in[10], d_in[11], d_in[12], d_in[13], d_in[14], d_in[15],
        (float*)d_ws);
    glow_kernel<<<dim3(NBLOCKS), dim3(BLOCK), 0, stream>>>(
        d_in[0], d_in[1], (const float*)d_ws, d_out);
}

// Round 13
// 129.341 us; speedup vs baseline: 1.2523x; 1.0039x over previous
//
#include <hip/hip_runtime.h>
#include <hip/hip_bf16.h>

#define N_SAMPLES 262144
#define NUM_FLOWS 8
#define BLOCK 256
#define WAVES 4
#define MT 2                                    // 16-sample col-tiles per wave (r9 config; MT=4 regressed r11)
#define SAMPLES_PER_BLOCK (WAVES * MT * 16)     // 128
#define NBLOCKS (N_SAMPLES / SAMPLES_PER_BLOCK) // 2048

// d_ws float layout:
#define OFF_W1    0        // 512
#define OFF_B1    512      // 512
#define OFF_B2    1024     // 512
#define OFF_B3    1536     // 32
#define OFF_CONST 1568     // 8 x 16: wm[9], els[3], sh[3], pad
#define OFF_LC    1696     // 12
#define OFF_MEAN  1708     // 3
#define OFF_LDB   1711     // 1
#define OFF_A3    1728     // W3 A-frags (quad-replicated), bf16: 8 x 2 x 64 x 8 = 16 KB
#define WS_PARAMS 5824     // floats (23296 B)
#define WS_W2_BYTE_OFF (WS_PARAMS * 4)  // 23296
#define SP_FLOATS 1536     // only W1/B1/B2 staged in LDS

typedef __attribute__((ext_vector_type(8))) short bf16x8;
typedef __attribute__((ext_vector_type(4))) short shortx4;
typedef __attribute__((ext_vector_type(4))) float floatx4;

union FragU { bf16x8 v; __hip_bfloat162 p[4]; __hip_bfloat16 e[8]; };
union S4U   { shortx4 v; __hip_bfloat16 e[4]; };

__device__ __forceinline__ float b2f(__hip_bfloat16 x) { return __bfloat162float(x); }

// dtype-flexible load/store; f32 flag is grid-uniform (sniffed from L_tril[0][1]==0).
__device__ __forceinline__ float ldv(const void* p, int i, bool f32) {
    return f32 ? ((const float*)p)[i] : b2f(((const __hip_bfloat16*)p)[i]);
}
__device__ __forceinline__ void stv(void* p, int i, float v, bool f32) {
    if (f32) ((float*)p)[i] = v;
    else ((__hip_bfloat16*)p)[i] = __float2bfloat16(v);
}

// ---------------- prep kernel: runs once per launch, 9 blocks ----------------
__global__ void prep_kernel(
    const void* __restrict__ g_L_tril,
    const void* __restrict__ g_base_mean,
    const void* __restrict__ g_an_log_scale,
    const void* __restrict__ g_an_shift,
    const void* __restrict__ g_perm_p,
    const void* __restrict__ g_sign_s,
    const void* __restrict__ g_lu_l,
    const void* __restrict__ g_lu_u,
    const void* __restrict__ g_lu_log_s,
    const void* __restrict__ g_W1,
    const void* __restrict__ g_b1,
    const void* __restrict__ g_W2,
    const void* __restrict__ g_b2,
    const void* __restrict__ g_W3,
    const void* __restrict__ g_b3,
    float* __restrict__ ws)
{
    const bool f32 = (((const float*)g_L_tril)[1] == 0.0f);
    const int f = blockIdx.x;
    const int tid = threadIdx.x;
    __hip_bfloat16* wsW2 = (__hip_bfloat16*)((char*)ws + WS_W2_BYTE_OFF);
    __hip_bfloat16* wsA3 = (__hip_bfloat16*)(ws + OFF_A3);

    if (f < NUM_FLOWS) {
        // W2 -> bf16 MFMA-A-frag order. flow-local elem (n,k) ->
        // frag (kc=k>>5, jt=n>>4), lane ((k>>3)&3)*16 + (n&15), slot k&7
        for (int i4 = tid; i4 < 1024; i4 += BLOCK) {
            int e = i4 << 2;
            int n = e >> 6, k = e & 63;
            int dst = ((k >> 5) * 4 + (n >> 4)) * 512 + (((k >> 3) & 3) * 16 + (n & 15)) * 8 + (k & 7);
            S4U u;
            if (f32) {
                float4 v = ((const float4*)g_W2)[f * 1024 + i4];
                u.e[0] = __float2bfloat16(v.x);
                u.e[1] = __float2bfloat16(v.y);
                u.e[2] = __float2bfloat16(v.z);
                u.e[3] = __float2bfloat16(v.w);
            } else {
                u.v = ((const shortx4*)g_W2)[f * 1024 + i4];
            }
            *(shortx4*)&wsW2[f * 4096 + dst] = u.v;
        }
        // W3 -> bf16 A-fragment, neuron-relabeled AND quad-replicated:
        // A3[m][k3] = W3[m & 3][n(k3)] so that C3[m=quad*4+r][col] = out[r][col]
        // for EVERY quad — no cross-lane broadcast needed in the main kernel.
        if (tid < 128) {
            int kc2 = tid >> 6, L = tid & 63;
            int m = L & 15, qd = L >> 4;
            FragU fr;
#pragma unroll
            for (int j = 0; j < 8; ++j) {
                int jt = ((j >> 2) << 1) | kc2;
                int r  = j & 3;
                int n  = jt * 16 + qd * 4 + r;
                fr.e[j] = __float2bfloat16(ldv(g_W3, f * 256 + (m & 3) * 64 + n, f32));
            }
            *(bf16x8*)&wsA3[(f * 2 + kc2) * 512 + L * 8] = fr.v;
        }
        if (tid < 64) {
            ws[OFF_W1 + f * 64 + tid] = ldv(g_W1, f * 64 + tid, f32);
            ws[OFF_B1 + f * 64 + tid] = ldv(g_b1, f * 64 + tid, f32);
            ws[OFF_B2 + f * 64 + tid] = ldv(g_b2, f * 64 + tid, f32);
        }
        if (tid < 4) ws[OFF_B3 + f * 4 + tid] = ldv(g_b3, f * 4 + tid, f32);
        if (tid == 0) {
            for (int d = 0; d < 3; ++d) {
                float ls = ldv(g_an_log_scale, f * 3 + d, f32);
                ws[OFF_CONST + f * 16 + 9 + d]  = __expf(ls);
                ws[OFF_CONST + f * 16 + 12 + d] = ldv(g_an_shift, f * 3 + d, f32);
            }
            float U[3][3], Lm[3][3], M[3][3], P[3][3];
            for (int i = 0; i < 3; ++i)
                for (int j = 0; j < 3; ++j) {
                    U[i][j]  = (j > i) ? ldv(g_lu_u, f * 9 + i * 3 + j, f32) : 0.f;
                    Lm[i][j] = (j < i) ? ldv(g_lu_l, f * 9 + i * 3 + j, f32) : (i == j ? 1.f : 0.f);
                    P[i][j]  = ldv(g_perm_p, f * 9 + i * 3 + j, f32);
                }
            for (int i = 0; i < 3; ++i)
                U[i][i] = ldv(g_sign_s, f * 3 + i, f32) * __expf(ldv(g_lu_log_s, f * 3 + i, f32));
            for (int i = 0; i < 3; ++i)
                for (int j = 0; j < 3; ++j) {
                    float s = 0.f;
                    for (int k = 0; k < 3; ++k) s += Lm[i][k] * U[k][j];
                    M[i][j] = s;
                }
            for (int i = 0; i < 3; ++i)
                for (int j = 0; j < 3; ++j) {
                    float s = 0.f;
                    for (int k = 0; k < 3; ++k) s += P[i][k] * M[k][j];
                    ws[OFF_CONST + f * 16 + i * 3 + j] = s;
                }
            ws[OFF_CONST + f * 16 + 15] = 0.f;
        }
    } else if (tid == 0) {
        // cholesky of cov = Lt Lt^T, mean, ldBase
        float Lt[3][3];
        for (int i = 0; i < 3; ++i)
            for (int j = 0; j < 3; ++j)
                Lt[i][j] = (j <= i) ? ldv(g_L_tril, i * 3 + j, f32) : 0.f;
        for (int i = 0; i < 3; ++i) Lt[i][i] += 1e-6f;
        float cov[3][3];
        for (int i = 0; i < 3; ++i)
            for (int j = 0; j < 3; ++j) {
                float s = 0.f;
                for (int k = 0; k < 3; ++k) s += Lt[i][k] * Lt[j][k];
                cov[i][j] = s;
            }
        float c00 = sqrtf(cov[0][0]);
        float c10 = cov[1][0] / c00, c20 = cov[2][0] / c00;
        float c11 = sqrtf(cov[1][1] - c10 * c10);
        float c21 = (cov[2][1] - c20 * c10) / c11;
        float c22 = sqrtf(cov[2][2] - c20 * c20 - c21 * c21);
        ws[OFF_LC + 0] = c00; ws[OFF_LC + 3] = c10; ws[OFF_LC + 4] = c11;
        ws[OFF_LC + 6] = c20; ws[OFF_LC + 7] = c21; ws[OFF_LC + 8] = c22;
        ws[OFF_LC + 1] = 0.f; ws[OFF_LC + 2] = 0.f; ws[OFF_LC + 5] = 0.f;
        ws[OFF_LC + 9] = 0.f; ws[OFF_LC + 10] = 0.f; ws[OFF_LC + 11] = 0.f;
        for (int d = 0; d < 3; ++d) ws[OFF_MEAN + d] = ldv(g_base_mean, d, f32);
        float ldb = 0.f;
        for (int i = 0; i < NUM_FLOWS * 3; ++i)
            ldb += ldv(g_an_log_scale, i, f32) + ldv(g_lu_log_s, i, f32);
        ws[OFF_LDB] = ldb;
    }
}

// ---------------- main kernel ----------------
// r12 structure + quad-replicated A3 (no cross-lane broadcast) + A3 moved from
// LDS to early global loads (LDS 23.5 -> 6.1 KB so all 8 grid-blocks/CU can be
// resident). launch_bounds (256,2): the only spill-free setting (r4/r7/r9/r12);
// (256,3)/(256,4) triggered 86-144 MB scratch (r5/r6).
__global__ __launch_bounds__(BLOCK, 2) void glow_kernel(
    const void* __restrict__ g_eps,
    const void* __restrict__ g_L_tril,
    const float* __restrict__ ws,
    void* __restrict__ g_out)
{
    const bool f32 = (((const float*)g_L_tril)[1] == 0.0f);

    // stage only the hot per-lane tables (W1/B1/B2) in LDS; ONE barrier.
    __shared__ __align__(16) float sP[SP_FLOATS];
    for (int i = threadIdx.x; i < SP_FLOATS / 4; i += BLOCK)
        ((float4*)sP)[i] = ((const float4*)ws)[i];
    __syncthreads();

    const __hip_bfloat16* wsW2 = (const __hip_bfloat16*)((const char*)ws + WS_W2_BYTE_OFF);
    const __hip_bfloat16* wsA3 = (const __hip_bfloat16*)(ws + OFF_A3);

    const int tid  = threadIdx.x;
    const int lane = tid & 63;
    const int wave = tid >> 6;
    const int quad = lane >> 4;
    const int col  = lane & 15;
    const int base = blockIdx.x * SAMPLES_PER_BLOCK + wave * (MT * 16);

    // z init (col layout: sample = base + mt*16 + col, replicated over quads)
    float zc0[MT], zc1[MT], zc2[MT], lda[MT];
    {
        const float l00 = ws[OFF_LC + 0], l10 = ws[OFF_LC + 3], l11 = ws[OFF_LC + 4];
        const float l20 = ws[OFF_LC + 6], l21 = ws[OFF_LC + 7], l22 = ws[OFF_LC + 8];
        const float m0 = ws[OFF_MEAN], m1 = ws[OFF_MEAN + 1], m2 = ws[OFF_MEAN + 2];
#pragma unroll
        for (int mt = 0; mt < MT; ++mt) {
            int g = base + mt * 16 + col;
            float e0 = ldv(g_eps, g * 3 + 0, f32);
            float e1 = ldv(g_eps, g * 3 + 1, f32);
            float e2 = ldv(g_eps, g * 3 + 2, f32);
            zc0[mt] = m0 + l00 * e0;
            zc1[mt] = m1 + l10 * e0 + l11 * e1;
            zc2[mt] = m2 + l20 * e0 + l21 * e1 + l22 * e2;
            lda[mt] = 0.f;
        }
    }

#pragma unroll 1
    for (int f = 0; f < NUM_FLOWS; ++f) {
        // A-frag + A3-frag loads issued early (global, L2-hot, lane-contiguous);
        // the affine + layer-1 VALU below covers their latency.
        bf16x8 Af[2][4];
#pragma unroll
        for (int kc = 0; kc < 2; ++kc)
#pragma unroll
            for (int jt = 0; jt < 4; ++jt)
                Af[kc][jt] = *(const bf16x8*)&wsW2[f * 4096 + ((kc * 4 + jt) * 64 + lane) * 8];
        bf16x8 A3f[2];
#pragma unroll
        for (int kc2 = 0; kc2 < 2; ++kc2)
            A3f[kc2] = *(const bf16x8*)&wsA3[((f * 2 + kc2) * 64 + lane) * 8];

        // b2 rows from LDS (4 reads)
        floatx4 b2q[4];
#pragma unroll
        for (int jt = 0; jt < 4; ++jt)
            b2q[jt] = *(const floatx4*)&sP[OFF_B2 + f * 64 + jt * 16 + quad * 4];

        // wave-uniform tables straight from global (scalar loads, off LDS pipe)
        const floatx4* cp = (const floatx4*)&ws[OFF_CONST + f * 16];
        floatx4 c0 = cp[0], c1 = cp[1], c2 = cp[2], c3 = cp[3];
        floatx4 b3v = *(const floatx4*)&ws[OFF_B3 + f * 4];

        // actnorm + 1x1 affine (fp32)
#pragma unroll
        for (int mt = 0; mt < MT; ++mt) {
            float t0 = c2[1] * (zc0[mt] + c3[0]);
            float t1 = c2[2] * (zc1[mt] + c3[1]);
            float t2 = c2[3] * (zc2[mt] + c3[2]);
            zc0[mt] = c0[0] * t0 + c0[1] * t1 + c0[2] * t2;
            zc1[mt] = c0[3] * t0 + c1[0] * t1 + c1[1] * t2;
            zc2[mt] = c1[2] * t0 + c1[3] * t1 + c2[0] * t2;
        }

        // layer 1 -> bf16 B fragments: h[k = kc*32+quad*8+i][m = col]
        FragU hB[MT][2];
#pragma unroll
        for (int kc = 0; kc < 2; ++kc) {
            const floatx4* w1p = (const floatx4*)&sP[OFF_W1 + f * 64 + kc * 32 + quad * 8];
            const floatx4* b1p = (const floatx4*)&sP[OFF_B1 + f * 64 + kc * 32 + quad * 8];
            floatx4 w1a = w1p[0], w1b = w1p[1];
            floatx4 b1a = b1p[0], b1b = b1p[1];
#pragma unroll
            for (int mt = 0; mt < MT; ++mt) {
                float z0 = zc0[mt];
#pragma unroll
                for (int w = 0; w < 2; ++w) {
                    float a0 = fmaxf(fmaf(z0, w1a[2 * w],     b1a[2 * w]),     0.f);
                    float a1 = fmaxf(fmaf(z0, w1a[2 * w + 1], b1a[2 * w + 1]), 0.f);
                    float b0 = fmaxf(fmaf(z0, w1b[2 * w],     b1b[2 * w]),     0.f);
                    float b1 = fmaxf(fmaf(z0, w1b[2 * w + 1], b1b[2 * w + 1]), 0.f);
                    hB[mt][kc].p[w]     = __float22bfloat162_rn(make_float2(a0, a1));
                    hB[mt][kc].p[2 + w] = __float22bfloat162_rn(make_float2(b0, b1));
                }
            }
        }

        // layer 2 (MFMA, b2 as C-init) -> in-register repack -> layer 3 (MFMA)
#pragma unroll
        for (int mt = 0; mt < MT; ++mt) {
            floatx4 a2[4];
#pragma unroll
            for (int jt = 0; jt < 4; ++jt) {
                floatx4 acc = __builtin_amdgcn_mfma_f32_16x16x32_bf16(Af[0][jt], hB[mt][0].v, b2q[jt], 0, 0, 0);
                a2[jt] = __builtin_amdgcn_mfma_f32_16x16x32_bf16(Af[1][jt], hB[mt][1].v, acc, 0, 0, 0);
            }
            // relu + pack: C pos (jt,r) -> B3 frag kc2 = jt&1, elem (jt>>1)*4 + r
            FragU h3[2];
#pragma unroll
            for (int jt = 0; jt < 4; ++jt) {
                int kc2 = jt & 1, pb = (jt >> 1) * 2;
                h3[kc2].p[pb]     = __float22bfloat162_rn(make_float2(fmaxf(a2[jt][0], 0.f), fmaxf(a2[jt][1], 0.f)));
                h3[kc2].p[pb + 1] = __float22bfloat162_rn(make_float2(fmaxf(a2[jt][2], 0.f), fmaxf(a2[jt][3], 0.f)));
            }
            floatx4 acc3 = {0.f, 0.f, 0.f, 0.f};
            acc3 = __builtin_amdgcn_mfma_f32_16x16x32_bf16(A3f[0], h3[0].v, acc3, 0, 0, 0);
            acc3 = __builtin_amdgcn_mfma_f32_16x16x32_bf16(A3f[1], h3[1].v, acc3, 0, 0, 0);
            // quad-replicated A3: every lane holds out[r][col] in acc3[r]
            float sh0 = acc3[0] + b3v[0];
            float sh1 = acc3[1] + b3v[1];
            float ls0 = acc3[2] + b3v[2];
            float ls1 = acc3[3] + b3v[3];
            zc1[mt] = fmaf(zc1[mt], __expf(ls0), sh0);
            zc2[mt] = fmaf(zc2[mt], __expf(ls1), sh1);
            lda[mt] += ls0 + ls1;
        }
    }

    if (quad == 0) {
        const float ldBase = ws[OFF_LDB];
#pragma unroll
        for (int mt = 0; mt < MT; ++mt) {
            int g = base + mt * 16 + col;
            float z1 = zc1[mt], z2 = zc2[mt];
            stv(g_out, g * 3 + 0, zc0[mt], f32);
            stv(g_out, g * 3 + 1, __expf(z1), f32);
            stv(g_out, g * 3 + 2, __expf(z2), f32);
            stv(g_out, 3 * N_SAMPLES + g, lda[mt] + ldBase + z1 + z2, f32);
        }
    }
}

extern "C" void kernel_launch(void* const* d_in, const int* in_sizes, int n_in,
                              void* d_out, int out_size, void* d_ws, size_t ws_size,
                              hipStream_t stream) {
    prep_kernel<<<dim3(NUM_FLOWS + 1), dim3(BLOCK), 0, stream>>>(
        d_in[1], d_in[2], d_in[3], d_in[4], d_in[5], d_in[6], d_in[7],
        d_in[8], d_in[9], d_in[10], d_in[11], d_in[12], d_in[13], d_in[14], d_in[15],
        (float*)d_ws);
    glow_kernel<<<dim3(NBLOCKS), dim3(BLOCK), 0, stream>>>(
        d_in[0], d_in[1], (const float*)d_ws, d_out);
}